// Round 11
// baseline (413.462 us; speedup 1.0000x reference)
//
#include <hip/hip_runtime.h>
#include <hip/hip_bf16.h>
#include <math.h>

#define BB    32
#define SS    1024
#define HID   1024
#define AT    512
#define NVOC  1000
#define NT    (BB*SS)

typedef unsigned short u16;
typedef __attribute__((ext_vector_type(8))) short s16x8;   // 8 bf16 (4 VGPRs)
typedef __attribute__((ext_vector_type(4))) float f32x4;   // MFMA acc

__device__ __forceinline__ float bf2f(u16 u) {
    union { unsigned int i; float f; } x; x.i = ((unsigned int)u) << 16; return x.f;
}
__device__ __forceinline__ u16 f2bf(float f) {
    union { float f; unsigned int i; } u; u.f = f;
    unsigned int r = u.i + 0x7fffu + ((u.i >> 16) & 1u);
    return (u16)(r >> 16);
}
__device__ __forceinline__ float4 ld4(const float* p) { return *(const float4*)p; }
__device__ __forceinline__ float4 ld4bf(const u16* p) {
    ushort4 v = *(const ushort4*)p;
    return make_float4(bf2f(v.x), bf2f(v.y), bf2f(v.z), bf2f(v.w));
}

// async global->LDS, 16B per lane; LDS dest = uniform base + lane*16 [m97]
__device__ __forceinline__ void gld16(const u16* g, u16* l) {
    __builtin_amdgcn_global_load_lds(
        (const __attribute__((address_space(1))) unsigned int*)g,
        (__attribute__((address_space(3))) unsigned int*)l,
        16, 0, 0);
}

struct Ptrs4f { const float* p[4]; };

__device__ __forceinline__ float blockReduceSum(float x) {
    #pragma unroll
    for (int off = 32; off > 0; off >>= 1) x += __shfl_down(x, off, 64);
    __shared__ float tmp[4];
    int lane = threadIdx.x & 63, wid = threadIdx.x >> 6;
    if (lane == 0) tmp[wid] = x;
    __syncthreads();
    if (threadIdx.x == 0) x = tmp[0] + tmp[1] + tmp[2] + tmp[3];
    return x; // valid on thread 0 only
}
__device__ __forceinline__ float waveReduceSum(float x) {
    #pragma unroll
    for (int off = 32; off > 0; off >>= 1) x += __shfl_down(x, off, 64);
    return x; // valid on lane 0
}

// ---------------- zoned prologue: PE16 + E16 + Wp16 ----------------
__global__ void k_prep(Ptrs4f E, const float* __restrict__ Wproj,
                       u16* __restrict__ PE16, u16* __restrict__ E16o, u16* __restrict__ Wp16) {
    int blk = blockIdx.x, tid = threadIdx.x;
    if (blk < 2048) {                       // PE table bf16, 512*1024/2 pairs
        int idx = blk*256 + tid;            // 0..524287
        int s = idx >> 9, i = idx & 511;
        const float l2_10000 = 13.287712379549449f;
        float denom = exp2f((2.f * (float)i / 1024.f) * l2_10000);
        float ang = (float)s / denom;
        unsigned int pack = ((unsigned int)f2bf(cosf(ang)) << 16) | f2bf(sinf(ang));
        *(unsigned int*)(PE16 + (size_t)s*1024 + 2*i) = pack;
    } else if (blk < 4048) {                // E -> bf16 (4 x 128000)
        int id2 = blk - 2048;
        int f = id2 / 500;
        int i = (id2 % 500)*256 + tid;      // 500*256 = 128000 exact
        E16o[(size_t)f*128000 + i] = f2bf(E.p[f][i]);
    } else {                                // Wproj -> bf16 (524288)
        int i = (blk - 4048)*256 + tid;
        Wp16[i] = f2bf(Wproj[i]);
    }
}

// ---------------- transpose fp32 -> bf16: out[c][r] = in[r][c] ----------------
__global__ void k_transp(Ptrs4f src, u16* __restrict__ dst, int R, int C) {
    const float* in = src.p[blockIdx.z];
    u16* out = dst + (size_t)blockIdx.z * R * C;
    int r0 = blockIdx.y*32, c0 = blockIdx.x*32;
    __shared__ float tt[32][33];
    tt[threadIdx.y][threadIdx.x] = in[(size_t)(r0 + threadIdx.y)*C + c0 + threadIdx.x];
    __syncthreads();
    out[(size_t)(c0 + threadIdx.y)*R + r0 + threadIdx.x] = f2bf(tt[threadIdx.x][threadIdx.y]);
}

// ---------------- stage A: W0f rows (1024) + Wcp (16) + CQ zero (32) ----------------
__global__ void k_pre1(const float* __restrict__ W0, const float* __restrict__ Wf,
                       const float* __restrict__ Wc, const float* __restrict__ Wproj,
                       float* __restrict__ W0f, float* __restrict__ Wcp, float* __restrict__ CQ) {
    int blk = blockIdx.x, tid = threadIdx.x;
    if (blk < 1024) {
        const float* row = W0 + (size_t)blk*1024;
        float a = 0.f;
        for (int j = tid; j < 1024; j += 256) a += row[j] * Wf[j];
        a = blockReduceSum(a);
        if (tid == 0) W0f[blk] = a;
    } else if (blk < 1040) {
        int r = blk - 1024; int c = r >> 2, is = r & 3; int i = is*256 + tid;
        float a = 0.f;
        for (int j = 0; j < 512; ++j) a += Wc[c*512 + j] * Wproj[(size_t)(512 + j)*1024 + i];
        Wcp[c*1024 + i] = a;
    } else {
        int r = blk - 1040;
        CQ[r*256 + tid] = 0.f;
    }
}

// ---------------- stage B: v (2048) + CQ j-split atomic (256) ----------------
__global__ void k_pre2(Ptrs4f W, const float* __restrict__ WV1, const float* __restrict__ WV2,
                       const float* __restrict__ W0f, const float* __restrict__ Wcp,
                       float* __restrict__ v, float* __restrict__ CQ) {
    int blk = blockIdx.x, tid = threadIdx.x;
    if (blk < 2048) {
        int h = blk >> 10, i = blk & 1023;
        const float* WV = h ? WV2 : WV1;
        const float* wf = W0f + h*512;
        float a = 0.f;
        for (int aa = tid; aa < 512; aa += 256) a += WV[(size_t)i*512 + aa] * wf[aa];
        a = blockReduceSum(a);
        if (tid == 0) v[h*1024 + i] = a;
    } else {
        int r = blk - 2048;              // 0..255
        int ns = r & 1, wc = (r >> 1) & 15, jc = r >> 5;   // jc 0..7
        int w = wc & 3, c = wc >> 2; int n = ns*256 + tid;
        const float* Ww = W.p[w];
        float a = 0.f;
        for (int j = jc*128; j < jc*128 + 128; ++j) a += Wcp[c*1024 + j] * Ww[(size_t)j*512 + n];
        atomicAdd(&CQ[(size_t)(w*4 + c)*512 + n], a);
    }
}

// ---------------- MFMA GEMM: C[M,N] = alpha * A[M,K] @ B[N,K]^T (bf16 in) ----------------
// BK=64, global_load_lds width 16, XOR-swizzled k-chunks (conflict-free, R8).
// STATS: quantize once, permuted 8B stores; column denominators d[k] = sum_q 2^s'
// accumulated via fp32 atomicAdd (NO max shift: |s| <~ 10, exp2 safe in fp32).
__device__ __forceinline__ void cstore(float* p, float v) { *p = v; }
__device__ __forceinline__ void cstore(u16* p, float v)   { *p = f2bf(v); }

template<typename CT, bool STATS, bool CTRANS>
__device__ __forceinline__ void mfma_gemm(const u16* __restrict__ A, const u16* __restrict__ B,
                                          CT* __restrict__ C, int M, int N, int K, float alpha,
                                          float* __restrict__ dcol, int m0, int n0) {
    __shared__ u16 As[128*64];
    __shared__ u16 Bs[128*64];
    const int tid = threadIdx.x;
    const int wave = tid >> 6, lane = tid & 63;
    const int quad = lane >> 4, l16 = lane & 15;
    const int wm = (wave >> 1)*64, wn = (wave & 1)*64;
    const int srow = lane >> 3;                 // 0..7 within the 8-row group
    const int scol = ((lane & 7) ^ srow) * 8;   // swizzled global k-chunk
    f32x4 acc[4][4] = {};

    for (int k0 = 0; k0 < K; k0 += 64) {
        #pragma unroll
        for (int p = 0; p < 4; ++p) {
            int rb = wave*32 + p*8;
            gld16(A + (size_t)(m0 + rb + srow)*K + k0 + scol, As + rb*64);
            gld16(B + (size_t)(n0 + rb + srow)*K + k0 + scol, Bs + rb*64);
        }
        __syncthreads();
        #pragma unroll
        for (int kk = 0; kk < 2; ++kk) {
            s16x8 af[4], bf[4];
            #pragma unroll
            for (int i = 0; i < 4; ++i) {
                int row = wm + i*16 + l16;
                af[i] = *(const s16x8*)(As + row*64 + (((kk*4 + quad) ^ (row & 7)) * 8));
            }
            #pragma unroll
            for (int j = 0; j < 4; ++j) {
                int row = wn + j*16 + l16;
                bf[j] = *(const s16x8*)(Bs + row*64 + (((kk*4 + quad) ^ (row & 7)) * 8));
            }
            #pragma unroll
            for (int i = 0; i < 4; ++i)
                #pragma unroll
                for (int j = 0; j < 4; ++j)
                    acc[i][j] = __builtin_amdgcn_mfma_f32_16x16x32_bf16(af[i], bf[j], acc[i][j], 0, 0, 0);
        }
        __syncthreads();
    }
    // C/D layout: col = lane&15, row = quad*4 + reg  [measured m89/m91]
    if (STATS) {
        #pragma unroll
        for (int i = 0; i < 4; ++i)
            #pragma unroll
            for (int r = 0; r < 4; ++r) {
                int gm = m0 + wm + i*16 + quad*4 + r;
                u16 b0 = f2bf(acc[i][0][r] * alpha);
                u16 b1 = f2bf(acc[i][1][r] * alpha);
                u16 b2 = f2bf(acc[i][2][r] * alpha);
                u16 b3 = f2bf(acc[i][3][r] * alpha);
                acc[i][0][r] = bf2f(b0); acc[i][1][r] = bf2f(b1);
                acc[i][2][r] = bf2f(b2); acc[i][3][r] = bf2f(b3);
                unsigned int lo = (unsigned int)b0 | ((unsigned int)b1 << 16);
                unsigned int hi = (unsigned int)b2 | ((unsigned int)b3 << 16);
                *(uint2*)((u16*)C + (size_t)gm*N + n0 + wn + l16*4) = make_uint2(lo, hi);
            }
        // column denominators (no max): d[k] += sum_q 2^s'
        #pragma unroll
        for (int j = 0; j < 4; ++j) {
            float sm = 0.f;
            #pragma unroll
            for (int i = 0; i < 4; ++i)
                #pragma unroll
                for (int r = 0; r < 4; ++r) sm += exp2f(acc[i][j][r]);
            sm += __shfl_xor(sm, 16, 64);
            sm += __shfl_xor(sm, 32, 64);
            if (quad == 0) atomicAdd(&dcol[n0 + wn + j*16 + l16], sm);
        }
    } else {
        #pragma unroll
        for (int i = 0; i < 4; ++i) {
            #pragma unroll
            for (int r = 0; r < 4; ++r) {
                int gm = m0 + wm + i*16 + quad*4 + r;
                if (gm < M) {
                    #pragma unroll
                    for (int j = 0; j < 4; ++j) {
                        int gn = n0 + wn + j*16 + l16;
                        if (CTRANS) cstore(C + (size_t)gn*M + gm, acc[i][j][r] * alpha);
                        else        cstore(C + (size_t)gm*N + gn, acc[i][j][r] * alpha);
                    }
                }
            }
        }
    }
}

// PW^T (64 blocks) + pre3 pv reduction (1024 blocks), zoned
__global__ __launch_bounds__(256) void k_pw_pre3(const u16* __restrict__ Wp16, const u16* __restrict__ Wt,
                                                 u16* __restrict__ PWT,
                                                 const float* __restrict__ Wproj, const float* __restrict__ v,
                                                 float* __restrict__ pv) {
    int blk = blockIdx.x;
    if (blk < 64) {
        int x = blk & 3, z = blk >> 2;      // z = f*4+w
        int f = z >> 2, w = z & 3;
        mfma_gemm<u16,false,true>(Wp16 + (size_t)f*128*1024, Wt + (size_t)w*512*1024,
                                  PWT + (size_t)z*512*128, 128, 512, 1024, 1.f,
                                  nullptr, 0, x*128);
    } else {
        int b2 = blk - 64, tid = threadIdx.x;
        int i = b2 & 127, fh = b2 >> 7; int f = fh >> 1, h = fh & 1;
        const float* row = Wproj + (size_t)(f*128 + i)*1024;
        const float* vh = v + h*1024;
        float a = 0.f;
        for (int j = tid; j < 1024; j += 256) a += row[j] * vh[j];
        a = blockReduceSum(a);
        if (tid == 0) pv[(size_t)fh*128 + i] = a;
    }
}

// TQK (z<16) + PEQ (z in 16..19), zoned
__global__ __launch_bounds__(256) void k_g_TP(const u16* __restrict__ E16, const u16* __restrict__ PWT,
                                              const u16* __restrict__ PE16, const u16* __restrict__ Wt,
                                              u16* __restrict__ TQK16, u16* __restrict__ PEQ16) {
    int z = blockIdx.z;
    if (z < 16) {
        int f = z >> 2;
        mfma_gemm<u16,false,false>(E16 + (size_t)f*128000, PWT + (size_t)z*512*128,
                   TQK16 + (size_t)z*1000*512, 1000, 512, 128, 1.f, nullptr,
                   blockIdx.y*128, blockIdx.x*128);
    } else {
        int w = z - 16;
        mfma_gemm<u16,false,false>(PE16, Wt + (size_t)w*512*1024, PEQ16 + (size_t)w*1024*512,
                   1024, 512, 1024, 1.f, nullptr, blockIdx.y*128, blockIdx.x*128);
    }
}

// scores (bf16, exp2-domain) + fused column-denominator atomics; XCD-swizzled
__global__ __launch_bounds__(256) void k_g_S(const u16* __restrict__ Q, const u16* __restrict__ K,
                                             u16* __restrict__ Sb, float alpha,
                                             float* __restrict__ d, int b0) {
    size_t b = blockIdx.z;
    int bx = (blockIdx.x % 4)*2 + (blockIdx.y % 2);
    int by = (blockIdx.x / 4)*4 + (blockIdx.y / 2);
    mfma_gemm<u16,true,false>(Q + b*SS*AT, K + b*SS*AT, Sb + b*SS*SS, 1024, 1024, 512, alpha,
                        d + ((size_t)(b0 + b) << 10), by*128, bx*128);
}

// ---------------- dots: Ut (2000 blk, wave-dots over E16) + pu (2048) + cu (8) ----------------
__global__ void k_dots(const u16* __restrict__ E16, const u16* __restrict__ PE16,
                       const float* __restrict__ Wcp, const float* __restrict__ v,
                       const float* __restrict__ pv,
                       float* __restrict__ Ut, float* __restrict__ pu, float* __restrict__ cu) {
    int id = blockIdx.x;
    if (id < 2000) {
        int wave = threadIdx.x >> 6, lane = threadIdx.x & 63;
        int d = id*4 + wave;                 // < 8000
        int f = d / 2000, h = (d / 1000) & 1, r = d % 1000;
        unsigned int e2 = *(const unsigned int*)(E16 + ((size_t)f*1000 + r)*128 + lane*2);
        const float* pvp = pv + (size_t)(f*2 + h)*128 + lane*2;
        float a = bf2f((u16)(e2 & 0xffff)) * pvp[0] + bf2f((u16)(e2 >> 16)) * pvp[1];
        a = waveReduceSum(a);
        if (lane == 0) Ut[(size_t)(f*2 + h)*1000 + r] = a;
    } else if (id < 4048) {
        int tq = id - 2000; int h = tq >> 10, s = tq & 1023;
        float4 a = ld4bf(PE16 + (size_t)s*1024 + threadIdx.x*4);
        float4 b = ld4(v + h*1024 + threadIdx.x*4);
        float p = a.x*b.x + a.y*b.y + a.z*b.z + a.w*b.w;
        p = blockReduceSum(p);
        if (threadIdx.x == 0) pu[h*1024 + s] = p;
    } else {
        int tq = id - 4048; int h = tq >> 2, c = tq & 3;
        float4 a = ld4(Wcp + c*1024 + threadIdx.x*4);
        float4 b = ld4(v + h*1024 + threadIdx.x*4);
        float p = a.x*b.x + a.y*b.y + a.z*b.z + a.w*b.w;
        p = blockReduceSum(p);
        if (threadIdx.x == 0) cu[h*4 + c] = p;
    }
}

// ---------------- gather for head h: 2 tokens/block, 8 bf16/thread; zeroes d ----------------
__device__ __forceinline__ void unpack8(uint4 v, float* x) {
    x[0] = bf2f((u16)(v.x & 0xffff)); x[1] = bf2f((u16)(v.x >> 16));
    x[2] = bf2f((u16)(v.y & 0xffff)); x[3] = bf2f((u16)(v.y >> 16));
    x[4] = bf2f((u16)(v.z & 0xffff)); x[5] = bf2f((u16)(v.z >> 16));
    x[6] = bf2f((u16)(v.w & 0xffff)); x[7] = bf2f((u16)(v.w >> 16));
}

__global__ void k_gather(const int* __restrict__ cate, const float* __restrict__ cont,
                         const u16* __restrict__ TQK, const float* __restrict__ CQ,
                         const u16* __restrict__ PEQ, const float* __restrict__ Ut,
                         const float* __restrict__ cu, const float* __restrict__ pu,
                         u16* __restrict__ Qh, u16* __restrict__ Kh,
                         float* __restrict__ u, float* __restrict__ dzero, int h) {
    int tid = threadIdx.x;
    if (blockIdx.x < 128) dzero[blockIdx.x*256 + tid] = 0.f;   // 32*1024 denom accumulator
    size_t t = (size_t)blockIdx.x*2 + (tid >> 7);
    int r = tid & 127;
    int s = (int)(t & 1023);
    int4 cc = *(const int4*)(cate + t*4);
    float4 cv = ld4(cont + t*4);
    int e = r >> 6;                 // 0=Q, 1=K
    int w = 2*h + e;
    int n = (r & 63)*8;
    const u16* t0 = TQK + ((size_t)(0*4  + w)*1000 + cc.x)*512 + n;
    const u16* t1 = TQK + ((size_t)(1*4  + w)*1000 + cc.y)*512 + n;
    const u16* t2 = TQK + ((size_t)(2*4  + w)*1000 + cc.z)*512 + n;
    const u16* t3 = TQK + ((size_t)(3*4  + w)*1000 + cc.w)*512 + n;
    const u16* pq = PEQ + ((size_t)w*1024 + s)*512 + n;
    const float* cq = CQ + (size_t)w*2048 + n;
    float a0[8], a1[8], a2[8], a3[8], ap[8];
    unpack8(*(const uint4*)t0, a0); unpack8(*(const uint4*)t1, a1);
    unpack8(*(const uint4*)t2, a2); unpack8(*(const uint4*)t3, a3);
    unpack8(*(const uint4*)pq, ap);
    unsigned int pack[4];
    #pragma unroll
    for (int jp = 0; jp < 4; ++jp) {
        float x0, x1;
        #pragma unroll
        for (int half = 0; half < 2; ++half) {
            int j = jp*2 + half;
            float x = a0[j] + a1[j] + a2[j] + a3[j] + ap[j]
                    + cv.x*cq[j] + cv.y*cq[512+j] + cv.z*cq[1024+j] + cv.w*cq[1536+j];
            if (half == 0) x0 = x; else x1 = x;
        }
        pack[jp] = ((unsigned int)f2bf(x1) << 16) | f2bf(x0);
    }
    u16* op = (e ? Kh : Qh) + t*512 + n;
    *(uint4*)op = make_uint4(pack[0], pack[1], pack[2], pack[3]);
    if (r == 0) {
        float uu = pu[h*1024 + s]
                 + Ut[(0*2 + h)*1000 + cc.x] + Ut[(1*2 + h)*1000 + cc.y]
                 + Ut[(2*2 + h)*1000 + cc.z] + Ut[(3*2 + h)*1000 + cc.w]
                 + cv.x*cu[h*4+0] + cv.y*cu[h*4+1] + cv.z*cu[h*4+2] + cv.w*cu[h*4+3];
        u[(size_t)h*NT + t] = uu;
    }
}

// ---------------- wexp = u/d into permuted slots ----------------
__global__ void k_wexp(const float* __restrict__ d, const float* __restrict__ u,
                       float* __restrict__ wexp, int b0) {
    int idx = b0*1024 + blockIdx.x*256 + threadIdx.x;   // b*1024 + k (actual)
    int b = idx >> 10, k = idx & 1023;
    int q = (k & ~63) | (((k & 15) << 2) | ((k & 63) >> 4));
    wexp[((size_t)b << 10) + q] = u[idx] / d[idx];
}

// ---------------- logits: wave-per-row over permuted S/wexp ----------------
__global__ void k_logit(const u16* __restrict__ Sb, const float* __restrict__ wexp,
                        float* __restrict__ logits, int b0, int init) {
    int wave = threadIdx.x >> 6, lane = threadIdx.x & 63;
    size_t tl = (size_t)blockIdx.x*4 + wave;
    size_t tabs = (size_t)b0*1024 + tl;
    int b = (int)(tabs >> 10);
    const u16* row = Sb + tl*1024;
    const float* wb = wexp + ((size_t)b << 10);
    float acc = 0.f;
    #pragma unroll
    for (int half = 0; half < 2; ++half) {
        int k = lane*8 + half*512;
        float4 s0 = ld4bf(row + k), s1 = ld4bf(row + k + 4);
        float4 w0 = ld4(wb + k),    w1 = ld4(wb + k + 4);
        acc += exp2f(s0.x)*w0.x + exp2f(s0.y)*w0.y + exp2f(s0.z)*w0.z + exp2f(s0.w)*w0.w
             + exp2f(s1.x)*w1.x + exp2f(s1.y)*w1.y + exp2f(s1.z)*w1.z + exp2f(s1.w)*w1.w;
    }
    acc = waveReduceSum(acc);
    if (lane == 0) { if (init) logits[tabs] = acc; else logits[tabs] += acc; }
}

// Output is FLOAT32 (reference returns fp32; harness reads fp32).
__global__ void k_final(const float* __restrict__ logits, float* __restrict__ out) {
    int t = blockIdx.x*256 + threadIdx.x;
    float x = logits[t];
    out[t] = 1.f / (1.f + expf(-x));
}

extern "C" void kernel_launch(void* const* d_in, const int* in_sizes, int n_in,
                              void* d_out, int out_size, void* d_ws, size_t ws_size,
                              hipStream_t stream) {
    const int*   cate = (const int*)d_in[0];
    const float* cont = (const float*)d_in[1];
    Ptrs4f E; E.p[0] = (const float*)d_in[4]; E.p[1] = (const float*)d_in[5];
              E.p[2] = (const float*)d_in[6]; E.p[3] = (const float*)d_in[7];
    const float* Wc    = (const float*)d_in[8];
    const float* Wproj = (const float*)d_in[9];
    Ptrs4f W; W.p[0] = (const float*)d_in[10];  // WQ1
              W.p[1] = (const float*)d_in[11];  // WK1
              W.p[2] = (const float*)d_in[13];  // WQ2
              W.p[3] = (const float*)d_in[14];  // WK2
    const float* WV1 = (const float*)d_in[12];
    const float* WV2 = (const float*)d_in[15];
    const float* W0  = (const float*)d_in[16];
    const float* Wf  = (const float*)d_in[17];

    char* base = (char*)d_ws;
    size_t off = 0;
    auto alloc = [&](size_t bytes) { void* p = base + off; off += (bytes + 255) & ~(size_t)255; return p; };
    u16*   PE16  = (u16*)  alloc(1048576ull*2);
    u16*   E16   = (u16*)  alloc(4ull*1000*128*2);
    u16*   Wt    = (u16*)  alloc(4ull*512*1024*2);
    u16*   Wp16  = (u16*)  alloc(512ull*1024*2);
    u16*   PWT   = (u16*)  alloc(16ull*512*128*2);
    u16*   TQK16 = (u16*)  alloc(16ull*1000*512*2);
    u16*   PEQ16 = (u16*)  alloc(4ull*1024*512*2);
    float* Wcp   = (float*)alloc(4*1024*4);
    float* W0f   = (float*)alloc(1024*4);
    float* vv    = (float*)alloc(2*1024*4);
    float* CQ    = (float*)alloc(16*512*4);
    float* pvb   = (float*)alloc(8*128*4);
    float* Ut    = (float*)alloc(8*1000*4);
    float* cu    = (float*)alloc(8*4);
    float* pu    = (float*)alloc(2*1024*4);
    float* ubuf  = (float*)alloc(2ull*NT*4);
    u16*   Qh    = (u16*)  alloc((size_t)NT*512*2);
    u16*   Kh    = (u16*)  alloc((size_t)NT*512*2);
    float* dbuf  = (float*)alloc(32ull*1024*4);
    float* wbuf  = (float*)alloc(32*1024*4);
    float* logits= (float*)alloc((size_t)NT*4);
    size_t sChunkBytes = (size_t)SS*SS*2;     // bf16 S
    size_t remain = (ws_size > off) ? (ws_size - off) : 0;
    int NB = (int)(remain / sChunkBytes);
    if (NB > 32) NB = 32;
    if (NB < 1) NB = 1;
    u16* Sbuf = (u16*)(base + off);

    const float alpha = 0.06375954951107036f;   // log2(e)/sqrt(512): exp2 domain

    k_prep<<<6096, 256, 0, stream>>>(E, Wproj, PE16, E16, Wp16);
    k_transp<<<dim3(16, 32, 4), dim3(32, 32), 0, stream>>>(W, Wt, 1024, 512);
    k_pre1<<<1072, 256, 0, stream>>>(W0, Wf, Wc, Wproj, W0f, Wcp, CQ);
    k_pre2<<<2304, 256, 0, stream>>>(W, WV1, WV2, W0f, Wcp, vv, CQ);
    k_pw_pre3<<<1088, 256, 0, stream>>>(Wp16, Wt, PWT, Wproj, vv, pvb);
    k_g_TP<<<dim3(4, 8, 20), 256, 0, stream>>>(E16, PWT, PE16, Wt, TQK16, PEQ16);
    k_dots<<<4056, 256, 0, stream>>>(E16, PE16, Wcp, vv, pvb, Ut, pu, cu);

    for (int h = 0; h < 2; ++h) {
        k_gather<<<NT/2, 256, 0, stream>>>(cate, cont, TQK16, CQ, PEQ16, Ut, cu, pu, Qh, Kh, ubuf, dbuf, h);
        for (int b0 = 0; b0 < 32; b0 += NB) {
            int nb = (32 - b0 < NB) ? (32 - b0) : NB;
            k_g_S<<<dim3(8, 8, nb), 256, 0, stream>>>(Qh + (size_t)b0*SS*AT, Kh + (size_t)b0*SS*AT, Sbuf, alpha, dbuf, b0);
            k_wexp<<<nb*4, 256, 0, stream>>>(dbuf, ubuf + (size_t)h*NT, wbuf, b0);
            k_logit<<<nb*256, 256, 0, stream>>>(Sbuf, wbuf, logits, b0, h == 0 ? 1 : 0);
        }
    }
    k_final<<<128, 256, 0, stream>>>(logits, (float*)d_out);
}

// Round 12
// 393.130 us; speedup vs baseline: 1.0517x; 1.0517x over previous
//
#include <hip/hip_runtime.h>
#include <hip/hip_bf16.h>
#include <math.h>

#define BB    32
#define SS    1024
#define HID   1024
#define AT    512
#define NVOC  1000
#define NT    (BB*SS)

typedef unsigned short u16;
typedef __attribute__((ext_vector_type(8))) short s16x8;   // 8 bf16 (4 VGPRs)
typedef __attribute__((ext_vector_type(4))) float f32x4;   // MFMA acc

__device__ __forceinline__ float bf2f(u16 u) {
    union { unsigned int i; float f; } x; x.i = ((unsigned int)u) << 16; return x.f;
}
__device__ __forceinline__ u16 f2bf(float f) {
    union { float f; unsigned int i; } u; u.f = f;
    unsigned int r = u.i + 0x7fffu + ((u.i >> 16) & 1u);
    return (u16)(r >> 16);
}
__device__ __forceinline__ float4 ld4(const float* p) { return *(const float4*)p; }
__device__ __forceinline__ float4 ld4bf(const u16* p) {
    ushort4 v = *(const ushort4*)p;
    return make_float4(bf2f(v.x), bf2f(v.y), bf2f(v.z), bf2f(v.w));
}

// async global->LDS, 16B per lane; LDS dest = uniform base + lane*16 [m97]
__device__ __forceinline__ void gld16(const u16* g, u16* l) {
    __builtin_amdgcn_global_load_lds(
        (const __attribute__((address_space(1))) unsigned int*)g,
        (__attribute__((address_space(3))) unsigned int*)l,
        16, 0, 0);
}

struct Ptrs4f { const float* p[4]; };

__device__ __forceinline__ float blockReduceSum(float x) {
    #pragma unroll
    for (int off = 32; off > 0; off >>= 1) x += __shfl_down(x, off, 64);
    __shared__ float tmp[4];
    int lane = threadIdx.x & 63, wid = threadIdx.x >> 6;
    if (lane == 0) tmp[wid] = x;
    __syncthreads();
    if (threadIdx.x == 0) x = tmp[0] + tmp[1] + tmp[2] + tmp[3];
    return x; // valid on thread 0 only
}
__device__ __forceinline__ float waveReduceSum(float x) {
    #pragma unroll
    for (int off = 32; off > 0; off >>= 1) x += __shfl_down(x, off, 64);
    return x; // valid on lane 0
}

// ---------------- zoned prologue: PE16 + E16 + Wp16 ----------------
__global__ void k_prep(Ptrs4f E, const float* __restrict__ Wproj,
                       u16* __restrict__ PE16, u16* __restrict__ E16o, u16* __restrict__ Wp16) {
    int blk = blockIdx.x, tid = threadIdx.x;
    if (blk < 2048) {                       // PE table bf16
        int idx = blk*256 + tid;            // 0..524287
        int s = idx >> 9, i = idx & 511;
        const float l2_10000 = 13.287712379549449f;
        float denom = exp2f((2.f * (float)i / 1024.f) * l2_10000);
        float ang = (float)s / denom;
        unsigned int pack = ((unsigned int)f2bf(cosf(ang)) << 16) | f2bf(sinf(ang));
        *(unsigned int*)(PE16 + (size_t)s*1024 + 2*i) = pack;
    } else if (blk < 4048) {                // E -> bf16 (4 x 128000)
        int id2 = blk - 2048;
        int f = id2 / 500;
        int i = (id2 % 500)*256 + tid;
        E16o[(size_t)f*128000 + i] = f2bf(E.p[f][i]);
    } else {                                // Wproj -> bf16 (524288)
        int i = (blk - 4048)*256 + tid;
        Wp16[i] = f2bf(Wproj[i]);
    }
}

// ---------------- transpose fp32 -> bf16: out[c][r] = in[r][c] ----------------
__global__ void k_transp(Ptrs4f src, u16* __restrict__ dst, int R, int C) {
    const float* in = src.p[blockIdx.z];
    u16* out = dst + (size_t)blockIdx.z * R * C;
    int r0 = blockIdx.y*32, c0 = blockIdx.x*32;
    __shared__ float tt[32][33];
    tt[threadIdx.y][threadIdx.x] = in[(size_t)(r0 + threadIdx.y)*C + c0 + threadIdx.x];
    __syncthreads();
    out[(size_t)(c0 + threadIdx.y)*R + r0 + threadIdx.x] = f2bf(tt[threadIdx.x][threadIdx.y]);
}

// ---------------- stage A: W0f rows (1024) + Wcp (16) + CQ zero (32) ----------------
__global__ void k_pre1(const float* __restrict__ W0, const float* __restrict__ Wf,
                       const float* __restrict__ Wc, const float* __restrict__ Wproj,
                       float* __restrict__ W0f, float* __restrict__ Wcp, float* __restrict__ CQ) {
    int blk = blockIdx.x, tid = threadIdx.x;
    if (blk < 1024) {
        const float* row = W0 + (size_t)blk*1024;
        float a = 0.f;
        for (int j = tid; j < 1024; j += 256) a += row[j] * Wf[j];
        a = blockReduceSum(a);
        if (tid == 0) W0f[blk] = a;
    } else if (blk < 1040) {
        int r = blk - 1024; int c = r >> 2, is = r & 3; int i = is*256 + tid;
        float a = 0.f;
        for (int j = 0; j < 512; ++j) a += Wc[c*512 + j] * Wproj[(size_t)(512 + j)*1024 + i];
        Wcp[c*1024 + i] = a;
    } else {
        int r = blk - 1040;
        CQ[r*256 + tid] = 0.f;
    }
}

// ---------------- stage B: v (2048) + CQ j-split atomic (256) ----------------
__global__ void k_pre2(Ptrs4f W, const float* __restrict__ WV1, const float* __restrict__ WV2,
                       const float* __restrict__ W0f, const float* __restrict__ Wcp,
                       float* __restrict__ v, float* __restrict__ CQ) {
    int blk = blockIdx.x, tid = threadIdx.x;
    if (blk < 2048) {
        int h = blk >> 10, i = blk & 1023;
        const float* WV = h ? WV2 : WV1;
        const float* wf = W0f + h*512;
        float a = 0.f;
        for (int aa = tid; aa < 512; aa += 256) a += WV[(size_t)i*512 + aa] * wf[aa];
        a = blockReduceSum(a);
        if (tid == 0) v[h*1024 + i] = a;
    } else {
        int r = blk - 2048;              // 0..255
        int ns = r & 1, wc = (r >> 1) & 15, jc = r >> 5;   // jc 0..7
        int w = wc & 3, c = wc >> 2; int n = ns*256 + tid;
        const float* Ww = W.p[w];
        float a = 0.f;
        for (int j = jc*128; j < jc*128 + 128; ++j) a += Wcp[c*1024 + j] * Ww[(size_t)j*512 + n];
        atomicAdd(&CQ[(size_t)(w*4 + c)*512 + n], a);
    }
}

// ---------------- MFMA GEMM: C[M,N] = alpha * A[M,K] @ B[N,K]^T (bf16 in) ----------------
// BK=64, global_load_lds width 16, XOR-swizzled k-chunks (conflict-free).
// STATS (R10-proven, 84 VGPR / 52 us): quantize once, permuted 8B stores, per-tile
// max+sum stats via shuffles + small LDS; R11's atomic/no-max variant hit the VGPR
// 85 cliff (92 regs -> 5 waves/SIMD) and regressed — do not reintroduce.
__device__ __forceinline__ void cstore(float* p, float v) { *p = v; }
__device__ __forceinline__ void cstore(u16* p, float v)   { *p = f2bf(v); }

template<typename CT, bool STATS, bool CTRANS>
__device__ __forceinline__ void mfma_gemm(const u16* __restrict__ A, const u16* __restrict__ B,
                                          CT* __restrict__ C, int M, int N, int K, float alpha,
                                          float* __restrict__ Pm, float* __restrict__ Pd,
                                          int m0, int n0) {
    __shared__ u16 As[128*64];
    __shared__ u16 Bs[128*64];
    const int tid = threadIdx.x;
    const int wave = tid >> 6, lane = tid & 63;
    const int quad = lane >> 4, l16 = lane & 15;
    const int wm = (wave >> 1)*64, wn = (wave & 1)*64;
    const int srow = lane >> 3;                 // 0..7 within the 8-row group
    const int scol = ((lane & 7) ^ srow) * 8;   // swizzled global k-chunk
    f32x4 acc[4][4] = {};

    for (int k0 = 0; k0 < K; k0 += 64) {
        #pragma unroll
        for (int p = 0; p < 4; ++p) {
            int rb = wave*32 + p*8;
            gld16(A + (size_t)(m0 + rb + srow)*K + k0 + scol, As + rb*64);
            gld16(B + (size_t)(n0 + rb + srow)*K + k0 + scol, Bs + rb*64);
        }
        __syncthreads();
        #pragma unroll
        for (int kk = 0; kk < 2; ++kk) {
            s16x8 af[4], bf[4];
            #pragma unroll
            for (int i = 0; i < 4; ++i) {
                int row = wm + i*16 + l16;
                af[i] = *(const s16x8*)(As + row*64 + (((kk*4 + quad) ^ (row & 7)) * 8));
            }
            #pragma unroll
            for (int j = 0; j < 4; ++j) {
                int row = wn + j*16 + l16;
                bf[j] = *(const s16x8*)(Bs + row*64 + (((kk*4 + quad) ^ (row & 7)) * 8));
            }
            #pragma unroll
            for (int i = 0; i < 4; ++i)
                #pragma unroll
                for (int j = 0; j < 4; ++j)
                    acc[i][j] = __builtin_amdgcn_mfma_f32_16x16x32_bf16(af[i], bf[j], acc[i][j], 0, 0, 0);
        }
        __syncthreads();
    }
    // C/D layout: col = lane&15, row = quad*4 + reg  [measured m89/m91]
    if (STATS) {
        #pragma unroll
        for (int i = 0; i < 4; ++i)
            #pragma unroll
            for (int r = 0; r < 4; ++r) {
                int gm = m0 + wm + i*16 + quad*4 + r;
                u16 b0 = f2bf(acc[i][0][r] * alpha);
                u16 b1 = f2bf(acc[i][1][r] * alpha);
                u16 b2 = f2bf(acc[i][2][r] * alpha);
                u16 b3 = f2bf(acc[i][3][r] * alpha);
                acc[i][0][r] = bf2f(b0); acc[i][1][r] = bf2f(b1);
                acc[i][2][r] = bf2f(b2); acc[i][3][r] = bf2f(b3);
                unsigned int lo = (unsigned int)b0 | ((unsigned int)b1 << 16);
                unsigned int hi = (unsigned int)b2 | ((unsigned int)b3 << 16);
                *(uint2*)((u16*)C + (size_t)gm*N + n0 + wn + l16*4) = make_uint2(lo, hi);
            }
        // per-tile column (query-axis) stats in exp2 domain (ACTUAL column space)
        __shared__ float sMax[4][64];
        __shared__ float sSum[4][64];
        #pragma unroll
        for (int j = 0; j < 4; ++j) {
            float mx = -3.4e38f;
            #pragma unroll
            for (int i = 0; i < 4; ++i)
                #pragma unroll
                for (int r = 0; r < 4; ++r) mx = fmaxf(mx, acc[i][j][r]);
            mx = fmaxf(mx, __shfl_xor(mx, 16, 64));
            mx = fmaxf(mx, __shfl_xor(mx, 32, 64));
            float sm = 0.f;
            #pragma unroll
            for (int i = 0; i < 4; ++i)
                #pragma unroll
                for (int r = 0; r < 4; ++r) sm += exp2f(acc[i][j][r] - mx);
            sm += __shfl_xor(sm, 16, 64);
            sm += __shfl_xor(sm, 32, 64);
            if (quad == 0) { sMax[wave][j*16 + l16] = mx; sSum[wave][j*16 + l16] = sm; }
        }
        __syncthreads();
        if (tid < 128) {
            int c = tid;
            int w0 = (c < 64) ? 0 : 1, ci = c & 63;
            float m0v = sMax[w0][ci],     s0 = sSum[w0][ci];
            float m1v = sMax[w0 + 2][ci], s1 = sSum[w0 + 2][ci];
            float mm = fmaxf(m0v, m1v);
            float ss = s0 * exp2f(m0v - mm) + s1 * exp2f(m1v - mm);
            Pm[n0 + c] = mm;     // caller pre-offsets Pm/Pd by (b*8 + mtile)*1024
            Pd[n0 + c] = ss;
        }
    } else {
        #pragma unroll
        for (int i = 0; i < 4; ++i) {
            #pragma unroll
            for (int r = 0; r < 4; ++r) {
                int gm = m0 + wm + i*16 + quad*4 + r;
                if (gm < M) {
                    #pragma unroll
                    for (int j = 0; j < 4; ++j) {
                        int gn = n0 + wn + j*16 + l16;
                        if (CTRANS) cstore(C + (size_t)gn*M + gm, acc[i][j][r] * alpha);
                        else        cstore(C + (size_t)gm*N + gn, acc[i][j][r] * alpha);
                    }
                }
            }
        }
    }
}

// PW^T (64 blocks) + pre3 pv reduction (1024 blocks), zoned
__global__ __launch_bounds__(256) void k_pw_pre3(const u16* __restrict__ Wp16, const u16* __restrict__ Wt,
                                                 u16* __restrict__ PWT,
                                                 const float* __restrict__ Wproj, const float* __restrict__ v,
                                                 float* __restrict__ pv) {
    int blk = blockIdx.x;
    if (blk < 64) {
        int x = blk & 3, z = blk >> 2;      // z = f*4+w
        int f = z >> 2, w = z & 3;
        mfma_gemm<u16,false,true>(Wp16 + (size_t)f*128*1024, Wt + (size_t)w*512*1024,
                                  PWT + (size_t)z*512*128, 128, 512, 1024, 1.f,
                                  nullptr, nullptr, 0, x*128);
    } else {
        int b2 = blk - 64, tid = threadIdx.x;
        int i = b2 & 127, fh = b2 >> 7; int f = fh >> 1, h = fh & 1;
        const float* row = Wproj + (size_t)(f*128 + i)*1024;
        const float* vh = v + h*1024;
        float a = 0.f;
        for (int j = tid; j < 1024; j += 256) a += row[j] * vh[j];
        a = blockReduceSum(a);
        if (tid == 0) pv[(size_t)fh*128 + i] = a;
    }
}

// TQK (z<16) + PEQ (z in 16..19), zoned
__global__ __launch_bounds__(256) void k_g_TP(const u16* __restrict__ E16, const u16* __restrict__ PWT,
                                              const u16* __restrict__ PE16, const u16* __restrict__ Wt,
                                              u16* __restrict__ TQK16, u16* __restrict__ PEQ16) {
    int z = blockIdx.z;
    if (z < 16) {
        int f = z >> 2;
        mfma_gemm<u16,false,false>(E16 + (size_t)f*128000, PWT + (size_t)z*512*128,
                   TQK16 + (size_t)z*1000*512, 1000, 512, 128, 1.f, nullptr, nullptr,
                   blockIdx.y*128, blockIdx.x*128);
    } else {
        int w = z - 16;
        mfma_gemm<u16,false,false>(PE16, Wt + (size_t)w*512*1024, PEQ16 + (size_t)w*1024*512,
                   1024, 512, 1024, 1.f, nullptr, nullptr, blockIdx.y*128, blockIdx.x*128);
    }
}

// scores (bf16, exp2-domain) + fused per-tile column stats; XCD-swizzled.
// __launch_bounds__(256,6): pin VGPR <= 85 (the 6-waves/SIMD cliff; R11's 92-reg
// variant fell to 5 waves and regressed 52->59 us).
__global__ __launch_bounds__(256, 6) void k_g_S(const u16* __restrict__ Q, const u16* __restrict__ K,
                                             u16* __restrict__ Sb, float alpha,
                                             float* __restrict__ Pm, float* __restrict__ Pd, int b0) {
    size_t b = blockIdx.z;
    int bx = (blockIdx.x % 4)*2 + (blockIdx.y % 2);
    int by = (blockIdx.x / 4)*4 + (blockIdx.y / 2);
    size_t po = ((b0 + b)*8 + by)*1024;
    mfma_gemm<u16,true,false>(Q + b*SS*AT, K + b*SS*AT, Sb + b*SS*SS, 1024, 1024, 512, alpha,
                        Pm + po, Pd + po, by*128, bx*128);
}

// ---------------- dots: Ut (2000 blk, wave-dots over E16) + pu (2048) + cu (8) ----------------
__global__ void k_dots(const u16* __restrict__ E16, const u16* __restrict__ PE16,
                       const float* __restrict__ Wcp, const float* __restrict__ v,
                       const float* __restrict__ pv,
                       float* __restrict__ Ut, float* __restrict__ pu, float* __restrict__ cu) {
    int id = blockIdx.x;
    if (id < 2000) {
        int wave = threadIdx.x >> 6, lane = threadIdx.x & 63;
        int d = id*4 + wave;                 // < 8000
        int f = d / 2000, h = (d / 1000) & 1, r = d % 1000;
        unsigned int e2 = *(const unsigned int*)(E16 + ((size_t)f*1000 + r)*128 + lane*2);
        const float* pvp = pv + (size_t)(f*2 + h)*128 + lane*2;
        float a = bf2f((u16)(e2 & 0xffff)) * pvp[0] + bf2f((u16)(e2 >> 16)) * pvp[1];
        a = waveReduceSum(a);
        if (lane == 0) Ut[(size_t)(f*2 + h)*1000 + r] = a;
    } else if (id < 4048) {
        int tq = id - 2000; int h = tq >> 10, s = tq & 1023;
        float4 a = ld4bf(PE16 + (size_t)s*1024 + threadIdx.x*4);
        float4 b = ld4(v + h*1024 + threadIdx.x*4);
        float p = a.x*b.x + a.y*b.y + a.z*b.z + a.w*b.w;
        p = blockReduceSum(p);
        if (threadIdx.x == 0) pu[h*1024 + s] = p;
    } else {
        int tq = id - 4048; int h = tq >> 2, c = tq & 3;
        float4 a = ld4(Wcp + c*1024 + threadIdx.x*4);
        float4 b = ld4(v + h*1024 + threadIdx.x*4);
        float p = a.x*b.x + a.y*b.y + a.z*b.z + a.w*b.w;
        p = blockReduceSum(p);
        if (threadIdx.x == 0) cu[h*4 + c] = p;
    }
}

// ---------------- gather for head h: 2 tokens/block, 8 bf16/thread ----------------
__device__ __forceinline__ void unpack8(uint4 v, float* x) {
    x[0] = bf2f((u16)(v.x & 0xffff)); x[1] = bf2f((u16)(v.x >> 16));
    x[2] = bf2f((u16)(v.y & 0xffff)); x[3] = bf2f((u16)(v.y >> 16));
    x[4] = bf2f((u16)(v.z & 0xffff)); x[5] = bf2f((u16)(v.z >> 16));
    x[6] = bf2f((u16)(v.w & 0xffff)); x[7] = bf2f((u16)(v.w >> 16));
}

__global__ void k_gather(const int* __restrict__ cate, const float* __restrict__ cont,
                         const u16* __restrict__ TQK, const float* __restrict__ CQ,
                         const u16* __restrict__ PEQ, const float* __restrict__ Ut,
                         const float* __restrict__ cu, const float* __restrict__ pu,
                         u16* __restrict__ Qh, u16* __restrict__ Kh,
                         float* __restrict__ u, int h) {
    int tid = threadIdx.x;
    size_t t = (size_t)blockIdx.x*2 + (tid >> 7);
    int r = tid & 127;
    int s = (int)(t & 1023);
    int4 cc = *(const int4*)(cate + t*4);
    float4 cv = ld4(cont + t*4);
    int e = r >> 6;                 // 0=Q, 1=K
    int w = 2*h + e;
    int n = (r & 63)*8;
    const u16* t0 = TQK + ((size_t)(0*4  + w)*1000 + cc.x)*512 + n;
    const u16* t1 = TQK + ((size_t)(1*4  + w)*1000 + cc.y)*512 + n;
    const u16* t2 = TQK + ((size_t)(2*4  + w)*1000 + cc.z)*512 + n;
    const u16* t3 = TQK + ((size_t)(3*4  + w)*1000 + cc.w)*512 + n;
    const u16* pq = PEQ + ((size_t)w*1024 + s)*512 + n;
    const float* cq = CQ + (size_t)w*2048 + n;
    float a0[8], a1[8], a2[8], a3[8], ap[8];
    unpack8(*(const uint4*)t0, a0); unpack8(*(const uint4*)t1, a1);
    unpack8(*(const uint4*)t2, a2); unpack8(*(const uint4*)t3, a3);
    unpack8(*(const uint4*)pq, ap);
    unsigned int pack[4];
    #pragma unroll
    for (int jp = 0; jp < 4; ++jp) {
        float x0, x1;
        #pragma unroll
        for (int half = 0; half < 2; ++half) {
            int j = jp*2 + half;
            float x = a0[j] + a1[j] + a2[j] + a3[j] + ap[j]
                    + cv.x*cq[j] + cv.y*cq[512+j] + cv.z*cq[1024+j] + cv.w*cq[1536+j];
            if (half == 0) x0 = x; else x1 = x;
        }
        pack[jp] = ((unsigned int)f2bf(x1) << 16) | f2bf(x0);
    }
    u16* op = (e ? Kh : Qh) + t*512 + n;
    *(uint4*)op = make_uint4(pack[0], pack[1], pack[2], pack[3]);
    if (r == 0) {
        float uu = pu[h*1024 + s]
                 + Ut[(0*2 + h)*1000 + cc.x] + Ut[(1*2 + h)*1000 + cc.y]
                 + Ut[(2*2 + h)*1000 + cc.z] + Ut[(3*2 + h)*1000 + cc.w]
                 + cv.x*cu[h*4+0] + cv.y*cu[h*4+1] + cv.z*cu[h*4+2] + cv.w*cu[h*4+3];
        u[(size_t)h*NT + t] = uu;
    }
}

// ---------------- combine per-tile stats (8 m-tiles) -> permuted wexp = u/d * 2^-m ----------------
__global__ void k_stats_combine(const float* __restrict__ Pm, const float* __restrict__ Pd,
                                const float* __restrict__ u, float* __restrict__ wexp, int b0) {
    int idx = b0*1024 + blockIdx.x*256 + threadIdx.x;   // b*1024 + k (actual)
    int b = idx >> 10, k = idx & 1023;
    float mx = -3.4e38f;
    #pragma unroll
    for (int mt = 0; mt < 8; ++mt) mx = fmaxf(mx, Pm[((size_t)b*8 + mt)*1024 + k]);
    float dd = 0.f;
    #pragma unroll
    for (int mt = 0; mt < 8; ++mt) dd += Pd[((size_t)b*8 + mt)*1024 + k]
                                       * exp2f(Pm[((size_t)b*8 + mt)*1024 + k] - mx);
    // permuted slot within the aligned 64-block: q = ((k&15)<<2) | ((k&63)>>4)
    int q = (k & ~63) | (((k & 15) << 2) | ((k & 63) >> 4));
    wexp[((size_t)b << 10) + q] = u[idx] / dd * exp2f(-mx);
}

// ---------------- logits: wave-per-row over permuted S/wexp, no barriers ----------------
__global__ void k_logit(const u16* __restrict__ Sb, const float* __restrict__ wexp,
                        float* __restrict__ logits, int b0, int init) {
    int wave = threadIdx.x >> 6, lane = threadIdx.x & 63;
    size_t tl = (size_t)blockIdx.x*4 + wave;
    size_t tabs = (size_t)b0*1024 + tl;
    int b = (int)(tabs >> 10);
    const u16* row = Sb + tl*1024;
    const float* wb = wexp + ((size_t)b << 10);
    float acc = 0.f;
    #pragma unroll
    for (int half = 0; half < 2; ++half) {
        int k = lane*8 + half*512;
        float4 s0 = ld4bf(row + k), s1 = ld4bf(row + k + 4);
        float4 w0 = ld4(wb + k),    w1 = ld4(wb + k + 4);
        acc += exp2f(s0.x)*w0.x + exp2f(s0.y)*w0.y + exp2f(s0.z)*w0.z + exp2f(s0.w)*w0.w
             + exp2f(s1.x)*w1.x + exp2f(s1.y)*w1.y + exp2f(s1.z)*w1.z + exp2f(s1.w)*w1.w;
    }
    acc = waveReduceSum(acc);
    if (lane == 0) { if (init) logits[tabs] = acc; else logits[tabs] += acc; }
}

// Output is FLOAT32 (reference returns fp32; harness reads fp32).
__global__ void k_final(const float* __restrict__ logits, float* __restrict__ out) {
    int t = blockIdx.x*256 + threadIdx.x;
    float x = logits[t];
    out[t] = 1.f / (1.f + expf(-x));
}

extern "C" void kernel_launch(void* const* d_in, const int* in_sizes, int n_in,
                              void* d_out, int out_size, void* d_ws, size_t ws_size,
                              hipStream_t stream) {
    const int*   cate = (const int*)d_in[0];
    const float* cont = (const float*)d_in[1];
    Ptrs4f E; E.p[0] = (const float*)d_in[4]; E.p[1] = (const float*)d_in[5];
              E.p[2] = (const float*)d_in[6]; E.p[3] = (const float*)d_in[7];
    const float* Wc    = (const float*)d_in[8];
    const float* Wproj = (const float*)d_in[9];
    Ptrs4f W; W.p[0] = (const float*)d_in[10];  // WQ1
              W.p[1] = (const float*)d_in[11];  // WK1
              W.p[2] = (const float*)d_in[13];  // WQ2
              W.p[3] = (const float*)d_in[14];  // WK2
    const float* WV1 = (const float*)d_in[12];
    const float* WV2 = (const float*)d_in[15];
    const float* W0  = (const float*)d_in[16];
    const float* Wf  = (const float*)d_in[17];

    char* base = (char*)d_ws;
    size_t off = 0;
    auto alloc = [&](size_t bytes) { void* p = base + off; off += (bytes + 255) & ~(size_t)255; return p; };
    u16*   PE16  = (u16*)  alloc(1048576ull*2);
    u16*   E16   = (u16*)  alloc(4ull*1000*128*2);
    u16*   Wt    = (u16*)  alloc(4ull*512*1024*2);
    u16*   Wp16  = (u16*)  alloc(512ull*1024*2);
    u16*   PWT   = (u16*)  alloc(16ull*512*128*2);
    u16*   TQK16 = (u16*)  alloc(16ull*1000*512*2);
    u16*   PEQ16 = (u16*)  alloc(4ull*1024*512*2);
    float* Wcp   = (float*)alloc(4*1024*4);
    float* W0f   = (float*)alloc(1024*4);
    float* vv    = (float*)alloc(2*1024*4);
    float* CQ    = (float*)alloc(16*512*4);
    float* pvb   = (float*)alloc(8*128*4);
    float* Ut    = (float*)alloc(8*1000*4);
    float* cu    = (float*)alloc(8*4);
    float* pu    = (float*)alloc(2*1024*4);
    float* ubuf  = (float*)alloc(2ull*NT*4);
    u16*   Qh    = (u16*)  alloc((size_t)NT*512*2);
    u16*   Kh    = (u16*)  alloc((size_t)NT*512*2);
    float* Pm    = (float*)alloc(32ull*8*1024*4);
    float* Pd    = (float*)alloc(32ull*8*1024*4);
    float* wbuf  = (float*)alloc(32*1024*4);
    float* logits= (float*)alloc((size_t)NT*4);
    size_t sChunkBytes = (size_t)SS*SS*2;     // bf16 S
    size_t remain = (ws_size > off) ? (ws_size - off) : 0;
    int NB = (int)(remain / sChunkBytes);
    if (NB > 32) NB = 32;
    if (NB < 1) NB = 1;
    u16* Sbuf = (u16*)(base + off);

    const float alpha = 0.06375954951107036f;   // log2(e)/sqrt(512): exp2 domain

    k_prep<<<6096, 256, 0, stream>>>(E, Wproj, PE16, E16, Wp16);
    k_transp<<<dim3(16, 32, 4), dim3(32, 32), 0, stream>>>(W, Wt, 1024, 512);
    k_pre1<<<1072, 256, 0, stream>>>(W0, Wf, Wc, Wproj, W0f, Wcp, CQ);
    k_pre2<<<2304, 256, 0, stream>>>(W, WV1, WV2, W0f, Wcp, vv, CQ);
    k_pw_pre3<<<1088, 256, 0, stream>>>(Wp16, Wt, PWT, Wproj, vv, pvb);
    k_g_TP<<<dim3(4, 8, 20), 256, 0, stream>>>(E16, PWT, PE16, Wt, TQK16, PEQ16);
    k_dots<<<4056, 256, 0, stream>>>(E16, PE16, Wcp, vv, pvb, Ut, pu, cu);

    for (int h = 0; h < 2; ++h) {
        k_gather<<<NT/2, 256, 0, stream>>>(cate, cont, TQK16, CQ, PEQ16, Ut, cu, pu, Qh, Kh, ubuf, h);
        for (int b0 = 0; b0 < 32; b0 += NB) {
            int nb = (32 - b0 < NB) ? (32 - b0) : NB;
            k_g_S<<<dim3(8, 8, nb), 256, 0, stream>>>(Qh + (size_t)b0*SS*AT, Kh + (size_t)b0*SS*AT, Sbuf, alpha, Pm, Pd, b0);
            k_stats_combine<<<nb*4, 256, 0, stream>>>(Pm, Pd, ubuf + (size_t)h*NT, wbuf, b0);
            k_logit<<<nb*256, 256, 0, stream>>>(Sbuf, wbuf, logits, b0, h == 0 ? 1 : 0);
        }
    }
    k_final<<<128, 256, 0, stream>>>(logits, (float*)d_out);
}

// Round 13
// 367.099 us; speedup vs baseline: 1.1263x; 1.0709x over previous
//
#include <hip/hip_runtime.h>
#include <hip/hip_bf16.h>
#include <math.h>

#define BB    32
#define SS    1024
#define HID   1024
#define AT    512
#define NVOC  1000
#define NT    (BB*SS)

typedef unsigned short u16;
typedef __attribute__((ext_vector_type(8))) short s16x8;   // 8 bf16 (4 VGPRs)
typedef __attribute__((ext_vector_type(4))) float f32x4;   // MFMA acc

__device__ __forceinline__ float bf2f(u16 u) {
    union { unsigned int i; float f; } x; x.i = ((unsigned int)u) << 16; return x.f;
}
__device__ __forceinline__ u16 f2bf(float f) {
    union { float f; unsigned int i; } u; u.f = f;
    unsigned int r = u.i + 0x7fffu + ((u.i >> 16) & 1u);
    return (u16)(r >> 16);
}
__device__ __forceinline__ float4 ld4(const float* p) { return *(const float4*)p; }
__device__ __forceinline__ float4 ld4bf(const u16* p) {
    ushort4 v = *(const ushort4*)p;
    return make_float4(bf2f(v.x), bf2f(v.y), bf2f(v.z), bf2f(v.w));
}
__device__ __forceinline__ void unpack8(uint4 v, float* x) {
    x[0] = bf2f((u16)(v.x & 0xffff)); x[1] = bf2f((u16)(v.x >> 16));
    x[2] = bf2f((u16)(v.y & 0xffff)); x[3] = bf2f((u16)(v.y >> 16));
    x[4] = bf2f((u16)(v.z & 0xffff)); x[5] = bf2f((u16)(v.z >> 16));
    x[6] = bf2f((u16)(v.w & 0xffff)); x[7] = bf2f((u16)(v.w >> 16));
}

// async global->LDS, 16B per lane; LDS dest = uniform base + lane*16 [m97]
__device__ __forceinline__ void gld16(const u16* g, u16* l) {
    __builtin_amdgcn_global_load_lds(
        (const __attribute__((address_space(1))) unsigned int*)g,
        (__attribute__((address_space(3))) unsigned int*)l,
        16, 0, 0);
}

struct Ptrs4f { const float* p[4]; };

__device__ __forceinline__ float blockReduceSum(float x) {
    #pragma unroll
    for (int off = 32; off > 0; off >>= 1) x += __shfl_down(x, off, 64);
    __shared__ float tmp[4];
    int lane = threadIdx.x & 63, wid = threadIdx.x >> 6;
    if (lane == 0) tmp[wid] = x;
    __syncthreads();
    if (threadIdx.x == 0) x = tmp[0] + tmp[1] + tmp[2] + tmp[3];
    return x; // valid on thread 0 only
}
__device__ __forceinline__ float waveReduceSum(float x) {
    #pragma unroll
    for (int off = 32; off > 0; off >>= 1) x += __shfl_down(x, off, 64);
    return x; // valid on lane 0
}

// ================= D1: PE16 + E16 + Wp16 + Wt transpose + W0f + zero(Wcp,CQ) ============
__global__ void k_s1(Ptrs4f E, const float* __restrict__ Wproj, Ptrs4f W,
                     const float* __restrict__ W0, const float* __restrict__ Wf,
                     u16* __restrict__ PE16, u16* __restrict__ E16o, u16* __restrict__ Wp16,
                     u16* __restrict__ Wt, float* __restrict__ W0f,
                     float* __restrict__ Wcp, float* __restrict__ CQ) {
    int blk = blockIdx.x, tid = threadIdx.x;
    if (blk < 2048) {                       // PE table bf16
        int idx = blk*256 + tid;
        int s = idx >> 9, i = idx & 511;
        const float l2_10000 = 13.287712379549449f;
        float denom = exp2f((2.f * (float)i / 1024.f) * l2_10000);
        float ang = (float)s / denom;
        unsigned int pack = ((unsigned int)f2bf(cosf(ang)) << 16) | f2bf(sinf(ang));
        *(unsigned int*)(PE16 + (size_t)s*1024 + 2*i) = pack;
    } else if (blk < 4048) {                // E -> bf16
        int id2 = blk - 2048;
        int f = id2 / 500;
        int i = (id2 % 500)*256 + tid;
        E16o[(size_t)f*128000 + i] = f2bf(E.p[f][i]);
    } else if (blk < 6096) {                // Wproj -> bf16
        int i = (blk - 4048)*256 + tid;
        Wp16[i] = f2bf(Wproj[i]);
    } else if (blk < 8144) {                // W transpose -> Wt (bf16), 32x32 tiles
        int tb = blk - 6096;
        int mat = tb >> 9, t2 = tb & 511;
        int cx = t2 & 15, ry = t2 >> 4;
        int r0 = ry*32, c0 = cx*32;
        const float* in = W.p[mat];
        u16* out = Wt + (size_t)mat*1024*512;
        __shared__ float tt[32][33];
        int tx = tid & 31, ty8 = tid >> 5;
        #pragma unroll
        for (int it = 0; it < 4; ++it)
            tt[ty8 + it*8][tx] = in[(size_t)(r0 + ty8 + it*8)*512 + c0 + tx];
        __syncthreads();
        #pragma unroll
        for (int it = 0; it < 4; ++it)
            out[(size_t)(c0 + ty8 + it*8)*1024 + r0 + tx] = f2bf(tt[tx][ty8 + it*8]);
    } else if (blk < 9168) {                // W0f rows
        int row = blk - 8144;
        const float* rp = W0 + (size_t)row*1024;
        float a = 0.f;
        for (int j = tid; j < 1024; j += 256) a += rp[j] * Wf[j];
        a = blockReduceSum(a);
        if (tid == 0) W0f[row] = a;
    } else {                                // zero Wcp (4096) + CQ (8192)
        int idx = (blk - 9168)*256 + tid;
        if (idx < 4096) Wcp[idx] = 0.f;
        else CQ[idx - 4096] = 0.f;
    }
}

// ================= D2: Wcp atomic j-split (64) + v (2048) =================
__global__ void k_s2(const float* __restrict__ Wc, const float* __restrict__ Wproj,
                     Ptrs4f W, const float* __restrict__ WV1, const float* __restrict__ WV2,
                     const float* __restrict__ W0f, float* __restrict__ Wcp, float* __restrict__ v) {
    int blk = blockIdx.x, tid = threadIdx.x;
    if (blk < 64) {                          // Wcp[c][i] += sum_{j in chunk} Wc*Wproj
        int c = blk >> 4, ic = (blk >> 2) & 3, jc = blk & 3;
        int i = ic*256 + tid;
        float a = 0.f;
        for (int j = jc*128; j < jc*128 + 128; ++j)
            a += Wc[c*512 + j] * Wproj[(size_t)(512 + j)*1024 + i];
        atomicAdd(&Wcp[c*1024 + i], a);
    } else {                                 // v
        int b2 = blk - 64;
        int h = b2 >> 10, i = b2 & 1023;
        const float* WV = h ? WV2 : WV1;
        const float* wf = W0f + h*512;
        float a = 0.f;
        for (int aa = tid; aa < 512; aa += 256) a += WV[(size_t)i*512 + aa] * wf[aa];
        a = blockReduceSum(a);
        if (tid == 0) v[h*1024 + i] = a;
    }
}

// ---------------- MFMA GEMM: C[M,N] = alpha * A[M,K] @ B[N,K]^T (bf16 in) ----------------
// BK=64, global_load_lds width 16, XOR-swizzled k-chunks (conflict-free).
// STATS (R10-proven, 84 VGPR / 52 us): quantize once, permuted 8B stores, per-tile
// max+sum stats. R11's atomic/no-max variant hit the VGPR-85 cliff (92 regs) — keep this.
__device__ __forceinline__ void cstore(float* p, float v) { *p = v; }
__device__ __forceinline__ void cstore(u16* p, float v)   { *p = f2bf(v); }

template<typename CT, bool STATS, bool CTRANS>
__device__ __forceinline__ void mfma_gemm(const u16* __restrict__ A, const u16* __restrict__ B,
                                          CT* __restrict__ C, int M, int N, int K, float alpha,
                                          float* __restrict__ Pm, float* __restrict__ Pd,
                                          int m0, int n0) {
    __shared__ u16 As[128*64];
    __shared__ u16 Bs[128*64];
    const int tid = threadIdx.x;
    const int wave = tid >> 6, lane = tid & 63;
    const int quad = lane >> 4, l16 = lane & 15;
    const int wm = (wave >> 1)*64, wn = (wave & 1)*64;
    const int srow = lane >> 3;
    const int scol = ((lane & 7) ^ srow) * 8;
    f32x4 acc[4][4] = {};

    for (int k0 = 0; k0 < K; k0 += 64) {
        #pragma unroll
        for (int p = 0; p < 4; ++p) {
            int rb = wave*32 + p*8;
            gld16(A + (size_t)(m0 + rb + srow)*K + k0 + scol, As + rb*64);
            gld16(B + (size_t)(n0 + rb + srow)*K + k0 + scol, Bs + rb*64);
        }
        __syncthreads();
        #pragma unroll
        for (int kk = 0; kk < 2; ++kk) {
            s16x8 af[4], bf[4];
            #pragma unroll
            for (int i = 0; i < 4; ++i) {
                int row = wm + i*16 + l16;
                af[i] = *(const s16x8*)(As + row*64 + (((kk*4 + quad) ^ (row & 7)) * 8));
            }
            #pragma unroll
            for (int j = 0; j < 4; ++j) {
                int row = wn + j*16 + l16;
                bf[j] = *(const s16x8*)(Bs + row*64 + (((kk*4 + quad) ^ (row & 7)) * 8));
            }
            #pragma unroll
            for (int i = 0; i < 4; ++i)
                #pragma unroll
                for (int j = 0; j < 4; ++j)
                    acc[i][j] = __builtin_amdgcn_mfma_f32_16x16x32_bf16(af[i], bf[j], acc[i][j], 0, 0, 0);
        }
        __syncthreads();
    }
    // C/D layout: col = lane&15, row = quad*4 + reg  [measured m89/m91]
    if (STATS) {
        #pragma unroll
        for (int i = 0; i < 4; ++i)
            #pragma unroll
            for (int r = 0; r < 4; ++r) {
                int gm = m0 + wm + i*16 + quad*4 + r;
                u16 b0 = f2bf(acc[i][0][r] * alpha);
                u16 b1 = f2bf(acc[i][1][r] * alpha);
                u16 b2 = f2bf(acc[i][2][r] * alpha);
                u16 b3 = f2bf(acc[i][3][r] * alpha);
                acc[i][0][r] = bf2f(b0); acc[i][1][r] = bf2f(b1);
                acc[i][2][r] = bf2f(b2); acc[i][3][r] = bf2f(b3);
                unsigned int lo = (unsigned int)b0 | ((unsigned int)b1 << 16);
                unsigned int hi = (unsigned int)b2 | ((unsigned int)b3 << 16);
                *(uint2*)((u16*)C + (size_t)gm*N + n0 + wn + l16*4) = make_uint2(lo, hi);
            }
        __shared__ float sMax[4][64];
        __shared__ float sSum[4][64];
        #pragma unroll
        for (int j = 0; j < 4; ++j) {
            float mx = -3.4e38f;
            #pragma unroll
            for (int i = 0; i < 4; ++i)
                #pragma unroll
                for (int r = 0; r < 4; ++r) mx = fmaxf(mx, acc[i][j][r]);
            mx = fmaxf(mx, __shfl_xor(mx, 16, 64));
            mx = fmaxf(mx, __shfl_xor(mx, 32, 64));
            float sm = 0.f;
            #pragma unroll
            for (int i = 0; i < 4; ++i)
                #pragma unroll
                for (int r = 0; r < 4; ++r) sm += exp2f(acc[i][j][r] - mx);
            sm += __shfl_xor(sm, 16, 64);
            sm += __shfl_xor(sm, 32, 64);
            if (quad == 0) { sMax[wave][j*16 + l16] = mx; sSum[wave][j*16 + l16] = sm; }
        }
        __syncthreads();
        if (tid < 128) {
            int c = tid;
            int w0 = (c < 64) ? 0 : 1, ci = c & 63;
            float m0v = sMax[w0][ci],     s0 = sSum[w0][ci];
            float m1v = sMax[w0 + 2][ci], s1 = sSum[w0 + 2][ci];
            float mm = fmaxf(m0v, m1v);
            float ss = s0 * exp2f(m0v - mm) + s1 * exp2f(m1v - mm);
            Pm[n0 + c] = mm;
            Pd[n0 + c] = ss;
        }
    } else {
        #pragma unroll
        for (int i = 0; i < 4; ++i) {
            #pragma unroll
            for (int r = 0; r < 4; ++r) {
                int gm = m0 + wm + i*16 + quad*4 + r;
                if (gm < M) {
                    #pragma unroll
                    for (int j = 0; j < 4; ++j) {
                        int gn = n0 + wn + j*16 + l16;
                        if (CTRANS) cstore(C + (size_t)gn*M + gm, acc[i][j][r] * alpha);
                        else        cstore(C + (size_t)gm*N + gn, acc[i][j][r] * alpha);
                    }
                }
            }
        }
    }
}

// ================= D3: PW GEMM (64) + CQ atomic (256) + pv (1024) =================
__global__ __launch_bounds__(256) void k_s3(const u16* __restrict__ Wp16, const u16* __restrict__ Wt,
                                            u16* __restrict__ PWT,
                                            Ptrs4f W, const float* __restrict__ Wcp, float* __restrict__ CQ,
                                            const float* __restrict__ Wproj, const float* __restrict__ v,
                                            float* __restrict__ pv) {
    int blk = blockIdx.x, tid = threadIdx.x;
    if (blk < 64) {
        int x = blk & 3, z = blk >> 2;
        int f = z >> 2, w = z & 3;
        mfma_gemm<u16,false,true>(Wp16 + (size_t)f*128*1024, Wt + (size_t)w*512*1024,
                                  PWT + (size_t)z*512*128, 128, 512, 1024, 1.f,
                                  nullptr, nullptr, 0, x*128);
    } else if (blk < 320) {
        int r = blk - 64;
        int ns = r & 1, wc = (r >> 1) & 15, jc = r >> 5;
        int w = wc & 3, c = wc >> 2; int n = ns*256 + tid;
        const float* Ww = W.p[w];
        float a = 0.f;
        for (int j = jc*128; j < jc*128 + 128; ++j) a += Wcp[c*1024 + j] * Ww[(size_t)j*512 + n];
        atomicAdd(&CQ[(size_t)(w*4 + c)*512 + n], a);
    } else {
        int b2 = blk - 320;
        int i = b2 & 127, fh = b2 >> 7; int f = fh >> 1, h = fh & 1;
        const float* row = Wproj + (size_t)(f*128 + i)*1024;
        const float* vh = v + h*1024;
        float a = 0.f;
        for (int j = tid; j < 1024; j += 256) a += row[j] * vh[j];
        a = blockReduceSum(a);
        if (tid == 0) pv[(size_t)fh*128 + i] = a;
    }
}

// ================= D4: TQK+PEQ GEMMs (640) + dots (4056) =================
__global__ __launch_bounds__(256) void k_s4(const u16* __restrict__ E16, const u16* __restrict__ PWT,
                                            const u16* __restrict__ PE16, const u16* __restrict__ Wt,
                                            u16* __restrict__ TQK16, u16* __restrict__ PEQ16,
                                            const float* __restrict__ Wcp, const float* __restrict__ v,
                                            const float* __restrict__ pv,
                                            float* __restrict__ Ut, float* __restrict__ pu, float* __restrict__ cu) {
    int blk = blockIdx.x;
    if (blk < 640) {
        int z = blk >> 5, r = blk & 31, y = r >> 2, x = r & 3;
        if (z < 16) {
            int f = z >> 2;
            mfma_gemm<u16,false,false>(E16 + (size_t)f*128000, PWT + (size_t)z*512*128,
                       TQK16 + (size_t)z*1000*512, 1000, 512, 128, 1.f, nullptr, nullptr,
                       y*128, x*128);
        } else {
            int w = z - 16;
            mfma_gemm<u16,false,false>(PE16, Wt + (size_t)w*512*1024, PEQ16 + (size_t)w*1024*512,
                       1024, 512, 1024, 1.f, nullptr, nullptr, y*128, x*128);
        }
        return;
    }
    int id = blk - 640;
    if (id < 2000) {
        int wave = threadIdx.x >> 6, lane = threadIdx.x & 63;
        int d = id*4 + wave;
        int f = d / 2000, h = (d / 1000) & 1, r = d % 1000;
        unsigned int e2 = *(const unsigned int*)(E16 + ((size_t)f*1000 + r)*128 + lane*2);
        const float* pvp = pv + (size_t)(f*2 + h)*128 + lane*2;
        float a = bf2f((u16)(e2 & 0xffff)) * pvp[0] + bf2f((u16)(e2 >> 16)) * pvp[1];
        a = waveReduceSum(a);
        if (lane == 0) Ut[(size_t)(f*2 + h)*1000 + r] = a;
    } else if (id < 4048) {
        int tq = id - 2000; int h = tq >> 10, s = tq & 1023;
        float4 a = ld4bf(PE16 + (size_t)s*1024 + threadIdx.x*4);
        float4 b = ld4(v + h*1024 + threadIdx.x*4);
        float p = a.x*b.x + a.y*b.y + a.z*b.z + a.w*b.w;
        p = blockReduceSum(p);
        if (threadIdx.x == 0) pu[h*1024 + s] = p;
    } else {
        int tq = id - 4048; int h = tq >> 2, c = tq & 3;
        float4 a = ld4(Wcp + c*1024 + threadIdx.x*4);
        float4 b = ld4(v + h*1024 + threadIdx.x*4);
        float p = a.x*b.x + a.y*b.y + a.z*b.z + a.w*b.w;
        p = blockReduceSum(p);
        if (threadIdx.x == 0) cu[h*4 + c] = p;
    }
}

// scores (bf16, exp2-domain) + fused per-tile column stats; XCD-swizzled.
// __launch_bounds__(256,6): pin VGPR <= 85 (the 6-waves/SIMD cliff; 92 regs = 5 waves regressed).
__global__ __launch_bounds__(256, 6) void k_g_S(const u16* __restrict__ Q, const u16* __restrict__ K,
                                             u16* __restrict__ Sb, float alpha,
                                             float* __restrict__ Pm, float* __restrict__ Pd, int b0) {
    size_t b = blockIdx.z;
    int bx = (blockIdx.x % 4)*2 + (blockIdx.y % 2);
    int by = (blockIdx.x / 4)*4 + (blockIdx.y / 2);
    size_t po = ((b0 + b)*8 + by)*1024;
    mfma_gemm<u16,true,false>(Q + b*SS*AT, K + b*SS*AT, Sb + b*SS*SS, 1024, 1024, 512, alpha,
                        Pm + po, Pd + po, by*128, bx*128);
}

// ---------------- gather for head h: 2 tokens/block, 8 bf16/thread ----------------
__global__ void k_gather(const int* __restrict__ cate, const float* __restrict__ cont,
                         const u16* __restrict__ TQK, const float* __restrict__ CQ,
                         const u16* __restrict__ PEQ, const float* __restrict__ Ut,
                         const float* __restrict__ cu, const float* __restrict__ pu,
                         u16* __restrict__ Qh, u16* __restrict__ Kh,
                         float* __restrict__ u, int h) {
    int tid = threadIdx.x;
    size_t t = (size_t)blockIdx.x*2 + (tid >> 7);
    int r = tid & 127;
    int s = (int)(t & 1023);
    int4 cc = *(const int4*)(cate + t*4);
    float4 cv = ld4(cont + t*4);
    int e = r >> 6;                 // 0=Q, 1=K
    int w = 2*h + e;
    int n = (r & 63)*8;
    const u16* t0 = TQK + ((size_t)(0*4  + w)*1000 + cc.x)*512 + n;
    const u16* t1 = TQK + ((size_t)(1*4  + w)*1000 + cc.y)*512 + n;
    const u16* t2 = TQK + ((size_t)(2*4  + w)*1000 + cc.z)*512 + n;
    const u16* t3 = TQK + ((size_t)(3*4  + w)*1000 + cc.w)*512 + n;
    const u16* pq = PEQ + ((size_t)w*1024 + s)*512 + n;
    const float* cq = CQ + (size_t)w*2048 + n;
    float a0[8], a1[8], a2[8], a3[8], ap[8];
    unpack8(*(const uint4*)t0, a0); unpack8(*(const uint4*)t1, a1);
    unpack8(*(const uint4*)t2, a2); unpack8(*(const uint4*)t3, a3);
    unpack8(*(const uint4*)pq, ap);
    unsigned int pack[4];
    #pragma unroll
    for (int jp = 0; jp < 4; ++jp) {
        float x0, x1;
        #pragma unroll
        for (int half = 0; half < 2; ++half) {
            int j = jp*2 + half;
            float x = a0[j] + a1[j] + a2[j] + a3[j] + ap[j]
                    + cv.x*cq[j] + cv.y*cq[512+j] + cv.z*cq[1024+j] + cv.w*cq[1536+j];
            if (half == 0) x0 = x; else x1 = x;
        }
        pack[jp] = ((unsigned int)f2bf(x1) << 16) | f2bf(x0);
    }
    u16* op = (e ? Kh : Qh) + t*512 + n;
    *(uint4*)op = make_uint4(pack[0], pack[1], pack[2], pack[3]);
    if (r == 0) {
        float uu = pu[h*1024 + s]
                 + Ut[(0*2 + h)*1000 + cc.x] + Ut[(1*2 + h)*1000 + cc.y]
                 + Ut[(2*2 + h)*1000 + cc.z] + Ut[(3*2 + h)*1000 + cc.w]
                 + cv.x*cu[h*4+0] + cv.y*cu[h*4+1] + cv.z*cu[h*4+2] + cv.w*cu[h*4+3];
        u[(size_t)h*NT + t] = uu;
    }
}

// ---------------- combine per-tile stats (8 m-tiles) -> permuted wexp = u/d * 2^-m ----------------
__global__ void k_stats_combine(const float* __restrict__ Pm, const float* __restrict__ Pd,
                                const float* __restrict__ u, float* __restrict__ wexp, int b0) {
    int idx = b0*1024 + blockIdx.x*256 + threadIdx.x;   // b*1024 + k (actual)
    int b = idx >> 10, k = idx & 1023;
    float mx = -3.4e38f;
    #pragma unroll
    for (int mt = 0; mt < 8; ++mt) mx = fmaxf(mx, Pm[((size_t)b*8 + mt)*1024 + k]);
    float dd = 0.f;
    #pragma unroll
    for (int mt = 0; mt < 8; ++mt) dd += Pd[((size_t)b*8 + mt)*1024 + k]
                                       * exp2f(Pm[((size_t)b*8 + mt)*1024 + k] - mx);
    int q = (k & ~63) | (((k & 15) << 2) | ((k & 63) >> 4));
    wexp[((size_t)b << 10) + q] = u[idx] / dd * exp2f(-mx);
}

// ---------------- logits: wave-per-row, reversed batch order (L2 tail reuse),
// 16B S loads; mode 1 fuses logits-add + sigmoid -> out ----------------
__global__ void k_logit(const u16* __restrict__ Sb, const float* __restrict__ wexp,
                        float* __restrict__ logits, float* __restrict__ out,
                        int b0, int mode) {
    int wave = threadIdx.x >> 6, lane = threadIdx.x & 63;
    size_t bi = (size_t)(gridDim.x - 1 - blockIdx.x);   // reverse: S-tail still in L2
    size_t tl = bi*4 + wave;
    size_t tabs = (size_t)b0*1024 + tl;
    int b = (int)(tabs >> 10);
    const u16* row = Sb + tl*1024;
    const float* wb = wexp + ((size_t)b << 10);
    float acc = 0.f;
    #pragma unroll
    for (int half = 0; half < 2; ++half) {
        int k = lane*8 + half*512;
        float sv[8];
        unpack8(*(const uint4*)(row + k), sv);
        float4 w0 = ld4(wb + k), w1 = ld4(wb + k + 4);
        acc += exp2f(sv[0])*w0.x + exp2f(sv[1])*w0.y + exp2f(sv[2])*w0.z + exp2f(sv[3])*w0.w
             + exp2f(sv[4])*w1.x + exp2f(sv[5])*w1.y + exp2f(sv[6])*w1.z + exp2f(sv[7])*w1.w;
    }
    acc = waveReduceSum(acc);
    if (lane == 0) {
        if (mode == 0) logits[tabs] = acc;
        else {
            float x = logits[tabs] + acc;
            out[tabs] = 1.f / (1.f + expf(-x));
        }
    }
}

extern "C" void kernel_launch(void* const* d_in, const int* in_sizes, int n_in,
                              void* d_out, int out_size, void* d_ws, size_t ws_size,
                              hipStream_t stream) {
    const int*   cate = (const int*)d_in[0];
    const float* cont = (const float*)d_in[1];
    Ptrs4f E; E.p[0] = (const float*)d_in[4]; E.p[1] = (const float*)d_in[5];
              E.p[2] = (const float*)d_in[6]; E.p[3] = (const float*)d_in[7];
    const float* Wc    = (const float*)d_in[8];
    const float* Wproj = (const float*)d_in[9];
    Ptrs4f W; W.p[0] = (const float*)d_in[10];  // WQ1
              W.p[1] = (const float*)d_in[11];  // WK1
              W.p[2] = (const float*)d_in[13];  // WQ2
              W.p[3] = (const float*)d_in[14];  // WK2
    const float* WV1 = (const float*)d_in[12];
    const float* WV2 = (const float*)d_in[15];
    const float* W0  = (const float*)d_in[16];
    const float* Wf  = (const float*)d_in[17];

    char* base = (char*)d_ws;
    size_t off = 0;
    auto alloc = [&](size_t bytes) { void* p = base + off; off += (bytes + 255) & ~(size_t)255; return p; };
    u16*   PE16  = (u16*)  alloc(1048576ull*2);
    u16*   E16   = (u16*)  alloc(4ull*1000*128*2);
    u16*   Wt    = (u16*)  alloc(4ull*512*1024*2);
    u16*   Wp16  = (u16*)  alloc(512ull*1024*2);
    u16*   PWT   = (u16*)  alloc(16ull*512*128*2);
    u16*   TQK16 = (u16*)  alloc(16ull*1000*512*2);
    u16*   PEQ16 = (u16*)  alloc(4ull*1024*512*2);
    float* Wcp   = (float*)alloc(4*1024*4);
    float* W0f   = (float*)alloc(1024*4);
    float* vv    = (float*)alloc(2*1024*4);
    float* CQ    = (float*)alloc(16*512*4);
    float* pvb   = (float*)alloc(8*128*4);
    float* Ut    = (float*)alloc(8*1000*4);
    float* cu    = (float*)alloc(8*4);
    float* pu    = (float*)alloc(2*1024*4);
    float* ubuf  = (float*)alloc(2ull*NT*4);
    u16*   Qh    = (u16*)  alloc((size_t)NT*512*2);
    u16*   Kh    = (u16*)  alloc((size_t)NT*512*2);
    float* Pm    = (float*)alloc(32ull*8*1024*4);
    float* Pd    = (float*)alloc(32ull*8*1024*4);
    float* wbuf  = (float*)alloc(32*1024*4);
    float* logits= (float*)alloc((size_t)NT*4);
    size_t sChunkBytes = (size_t)SS*SS*2;     // bf16 S
    size_t remain = (ws_size > off) ? (ws_size - off) : 0;
    int NB = (int)(remain / sChunkBytes);
    if (NB > 32) NB = 32;
    if (NB < 1) NB = 1;
    u16* Sbuf = (u16*)(base + off);

    const float alpha = 0.06375954951107036f;   // log2(e)/sqrt(512): exp2 domain

    k_s1<<<9216, 256, 0, stream>>>(E, Wproj, W, W0, Wf, PE16, E16, Wp16, Wt, W0f, Wcp, CQ);
    k_s2<<<2112, 256, 0, stream>>>(Wc, Wproj, W, WV1, WV2, W0f, Wcp, vv);
    k_s3<<<1344, 256, 0, stream>>>(Wp16, Wt, PWT, W, Wcp, CQ, Wproj, vv, pvb);
    k_s4<<<4696, 256, 0, stream>>>(E16, PWT, PE16, Wt, TQK16, PEQ16, Wcp, vv, pvb, Ut, pu, cu);

    for (int h = 0; h < 2; ++h) {
        k_gather<<<NT/2, 256, 0, stream>>>(cate, cont, TQK16, CQ, PEQ16, Ut, cu, pu, Qh, Kh, ubuf, h);
        for (int b0 = 0; b0 < 32; b0 += NB) {
            int nb = (32 - b0 < NB) ? (32 - b0) : NB;
            k_g_S<<<dim3(8, 8, nb), 256, 0, stream>>>(Qh + (size_t)b0*SS*AT, Kh + (size_t)b0*SS*AT, Sbuf, alpha, Pm, Pd, b0);
            k_stats_combine<<<nb*4, 256, 0, stream>>>(Pm, Pd, ubuf + (size_t)h*NT, wbuf, b0);
            k_logit<<<nb*256, 256, 0, stream>>>(Sbuf, wbuf, logits, (float*)d_out, b0, h);
        }
    }
}